// Round 1
// 159.230 us; speedup vs baseline: 1.0729x; 1.0729x over previous
//
#include <hip/hip_runtime.h>

// VQ-VAE quantize: z [32,64,64,64] NCHW fp32, codebook [512,64] fp32.
// out = quantized (8388608 fp32, NCHW) ++ loss scalar. N=131072, D=64, K=512.
//
// R9: latency-bound fix (MfmaUtil 9.7 / VALUBusy 19 / HBM 6% -> all idle).
// - Double-buffered codebook tiles staged via __builtin_amdgcn_global_load_lds,
//   prefetch of tile kt+1 issued BEFORE compute of tile kt; ONE barrier per
//   tile (the compiler's vmcnt(0) drain at __syncthreads lands after a full
//   tile of MFMA+VALU -> staging latency hidden). T3-minimum 2-phase.
// - zT LDS staging removed entirely: A-frags / epilogue read z straight from
//   global (coalesced, L3-warm); fallback stages one 64-float row in zrow_s.
//   Frees LDS for the 2nd tile buffer while keeping 2 blocks/CU (~77 KB).
// - Fallback rows compacted into a list (LDS atomic) so clean blocks skip
//   the 128-iteration scan.
// Numerics unchanged vs R8: 3-pass hi/lo bf16 MFMA rank, TAU=4e-3 gap ->
// np-bit-exact block rescan; outputs are exact gathers -> absmax 0.0.

typedef __bf16 bf8 __attribute__((ext_vector_type(8)));
typedef float  f4  __attribute__((ext_vector_type(4)));

#define Dz    64
#define HWz   4096
#define Nz    131072
#define QSIZE ((size_t)Nz * Dz)     // 8388608
#define CROW  72                    // split-cb row stride (ushorts) = 144B
#define TILE_USHORT 18432           // one 128-code tile (hi+lo) in ushorts
#define TILE_BYTES  36864
#define CB_WS_BYTES (4 * 36864)     // 147456
#define TAU   4e-3f

#define MFMA(A, B, C) __builtin_amdgcn_mfma_f32_16x16x32_bf16(A, B, C, 0, 0, 0)

// wave-uniform LDS dest (base + lane*16), per-lane global src
__device__ __forceinline__ void gll16(const void* g, void* l) {
    __builtin_amdgcn_global_load_lds(
        (const __attribute__((address_space(1))) void*)g,
        (__attribute__((address_space(3))) void*)l, 16, 0, 0);
}

// ---------- prep: split codebook to bf16 hi/lo (padded tiles) + exact cn ----
__global__ __launch_bounds__(256) void vq_prep(const float* __restrict__ cb,
                                               unsigned short* __restrict__ cbws,
                                               float* __restrict__ cnws) {
    const int k = blockIdx.x * 256 + threadIdx.x;   // 0..511
    const float4* row = (const float4*)(cb + (size_t)k * 64);
    {   // numpy pairwise-8 sumsq (squares round before add)
#pragma clang fp contract(off)
        float r0, r1, r2, r3, r4, r5, r6, r7;
        {
            float4 f0 = row[0], f1 = row[1];
            r0 = f0.x * f0.x; r1 = f0.y * f0.y; r2 = f0.z * f0.z; r3 = f0.w * f0.w;
            r4 = f1.x * f1.x; r5 = f1.y * f1.y; r6 = f1.z * f1.z; r7 = f1.w * f1.w;
        }
#pragma unroll
        for (int m = 1; m < 8; ++m) {
            float4 f0 = row[2 * m], f1 = row[2 * m + 1];
            r0 = r0 + f0.x * f0.x; r1 = r1 + f0.y * f0.y;
            r2 = r2 + f0.z * f0.z; r3 = r3 + f0.w * f0.w;
            r4 = r4 + f1.x * f1.x; r5 = r5 + f1.y * f1.y;
            r6 = r6 + f1.z * f1.z; r7 = r7 + f1.w * f1.w;
        }
        cnws[k] = ((r0 + r1) + (r2 + r3)) + ((r4 + r5) + (r6 + r7));
    }
    unsigned short* hi = cbws + (size_t)(k >> 7) * TILE_USHORT + (k & 127) * CROW;
    unsigned short* lo = hi + TILE_USHORT / 2;      // +9216 ushorts = 18432B
#define SPLIT1(x, i)                                                   \
    {   __bf16 h = (__bf16)(x); float rr = (x) - (float)h;             \
        hi[i] = __builtin_bit_cast(unsigned short, h);                 \
        lo[i] = __builtin_bit_cast(unsigned short, (__bf16)rr); }
#pragma unroll
    for (int i = 0; i < 16; ++i) {
        float4 f = row[i];
        SPLIT1(f.x, 4 * i + 0) SPLIT1(f.y, 4 * i + 1)
        SPLIT1(f.z, 4 * i + 2) SPLIT1(f.w, 4 * i + 3)
    }
#undef SPLIT1
}

// ---------- main ----------
#define DECL8(P) float P##0, P##1, P##2, P##3, P##4, P##5, P##6, P##7;
#define DECI8(P) int   P##0, P##1, P##2, P##3, P##4, P##5, P##6, P##7;

// best/second update: order matters (second from OLD best).
#define UPDR(ACCE, B, K, S)                                            \
    {   const float vv = __builtin_fmaf(ACCE, -2.0f, cnv);             \
        S = fminf(S, fmaxf(B, vv));                                    \
        K = (vv < B) ? kcand : K;                                      \
        B = fminf(B, vv); }

#define REDR(B, K, S)                                                  \
    _Pragma("unroll")                                                  \
    for (int mm = 1; mm < 16; mm <<= 1) {                              \
        const float ob = __shfl_xor(B, mm, 64);                        \
        const int   ok = __shfl_xor(K, mm, 64);                        \
        const float os = __shfl_xor(S, mm, 64);                        \
        S = fminf(fminf(S, os), fmaxf(B, ob));                         \
        K = (ob < B) ? ok : K;                                         \
        B = fminf(B, ob); }

__global__ __launch_bounds__(256, 2) void vq_main(
    const float* __restrict__ z, const float* __restrict__ cb,
    const unsigned short* __restrict__ cbws, const float* __restrict__ cnws,
    float* __restrict__ out, float* __restrict__ loss_accum,
    unsigned int* __restrict__ done_counter) {
    __shared__ __attribute__((aligned(16))) unsigned short cbS[2][TILE_USHORT];
    __shared__ __attribute__((aligned(16))) float cn_s[512];
    __shared__ int    idx_s[128];
    __shared__ float  zrow_s[64];
    __shared__ float  wredD[4];
    __shared__ int    wredK[4];
    __shared__ float  wsum[4];
    __shared__ int    nfb;
    __shared__ unsigned char fbrows[128];

    const int t  = threadIdx.x;
    const int w  = t >> 6;
    const int l  = t & 63;
    const int q  = l >> 4;
    const int m16 = l & 15;
    const int n0g = blockIdx.x * 128;
    const int b   = n0g >> 12;
    const int s0  = n0g & 4095;
    const float* zB = z + (size_t)b * (Dz * HWz);

    // ---- issue tile0 + cn async into LDS (9+ chunks of 1024B per wave)
    {
        const char* tsrc = (const char*)cbws;
        char* tdst = (char*)&cbS[0][0];
#pragma unroll
        for (int i = 0; i < 9; ++i) {
            const int c = 9 * w + i;
            gll16(tsrc + c * 1024 + l * 16, tdst + c * 1024);
        }
        if (w < 2)
            gll16((const char*)cnws + w * 1024 + l * 16, (char*)cn_s + w * 1024);
        if (t == 0) nfb = 0;
    }

    // ---- build A fragments straight from global (latency overlaps tile0 gll)
    bf8 ah00, ah01, al00, al01, ah10, ah11, al10, al11;
    {
        const int pA = 32 * w + m16, pB = pA + 16;
        const float* zq = zB + s0;
#define BUILDA(AH, AL, P, KC)                                          \
        _Pragma("unroll")                                              \
        for (int j = 0; j < 8; ++j) {                                  \
            const float v = zq[(size_t)((KC) * 32 + q * 8 + j) * HWz + (P)]; \
            const __bf16 h = (__bf16)v;                                \
            AH[j] = h;                                                 \
            AL[j] = (__bf16)(v - (float)h);                            \
        }
        BUILDA(ah00, al00, pA, 0) BUILDA(ah01, al01, pA, 1)
        BUILDA(ah10, al10, pB, 0) BUILDA(ah11, al11, pB, 1)
#undef BUILDA
    }
    __syncthreads();    // vmcnt(0) drain: tile0 + cn landed

    // ---- K loop: 4 tiles x 128 codes, double-buffered w/ async prefetch.
    const float INF = __builtin_inff();
    DECL8(bd) DECI8(bk) DECL8(sd)
    bd0=INF;bd1=INF;bd2=INF;bd3=INF;bd4=INF;bd5=INF;bd6=INF;bd7=INF;
    sd0=INF;sd1=INF;sd2=INF;sd3=INF;sd4=INF;sd5=INF;sd6=INF;sd7=INF;
    bk0=0;bk1=0;bk2=0;bk3=0;bk4=0;bk5=0;bk6=0;bk7=0;

    for (int kt = 0; kt < 4; ++kt) {
        const unsigned short* cbuf = &cbS[kt & 1][0];
        if (kt < 3) {   // issue next tile BEFORE compute; lands by next barrier
            const char* tsrc = (const char*)(cbws + (size_t)(kt + 1) * TILE_USHORT);
            char* tdst = (char*)&cbS[(kt + 1) & 1][0];
#pragma unroll
            for (int i = 0; i < 9; ++i) {
                const int c = 9 * w + i;
                gll16(tsrc + c * 1024 + l * 16, tdst + c * 1024);
            }
        }
        const int k0 = kt * 128;
#pragma unroll 2
        for (int n0 = 0; n0 < 128; n0 += 16) {
            const int nlane = n0 + m16;
            const int hoff = nlane * CROW + q * 8;          // ushorts
            const bf8 bh0 = *(const bf8*)(cbuf + hoff);
            const bf8 bh1 = *(const bf8*)(cbuf + hoff + 32);
            const bf8 bl0 = *(const bf8*)(cbuf + hoff + TILE_USHORT / 2);
            const bf8 bl1 = *(const bf8*)(cbuf + hoff + TILE_USHORT / 2 + 32);
            f4 acc0 = {0.f, 0.f, 0.f, 0.f}, acc1 = {0.f, 0.f, 0.f, 0.f};
            acc0 = MFMA(ah00, bh0, acc0); acc0 = MFMA(ah01, bh1, acc0);
            acc1 = MFMA(ah10, bh0, acc1); acc1 = MFMA(ah11, bh1, acc1);
            acc0 = MFMA(al00, bh0, acc0); acc0 = MFMA(al01, bh1, acc0);
            acc1 = MFMA(al10, bh0, acc1); acc1 = MFMA(al11, bh1, acc1);
            acc0 = MFMA(ah00, bl0, acc0); acc0 = MFMA(ah01, bl1, acc0);
            acc1 = MFMA(ah10, bl0, acc1); acc1 = MFMA(ah11, bl1, acc1);
            const float cnv = cn_s[k0 + nlane];
            const int kcand = k0 + nlane;
            UPDR(acc0[0], bd0, bk0, sd0) UPDR(acc0[1], bd1, bk1, sd1)
            UPDR(acc0[2], bd2, bk2, sd2) UPDR(acc0[3], bd3, bk3, sd3)
            UPDR(acc1[0], bd4, bk4, sd4) UPDR(acc1[1], bd5, bk5, sd5)
            UPDR(acc1[2], bd6, bk6, sd6) UPDR(acc1[3], bd7, bk7, sd7)
        }
        __syncthreads();    // all reads of cbuf done; next tile's gll drained
    }

    // ---- cross-lane reduce (16-lane groups hold one row each) + flag.
    REDR(bd0, bk0, sd0) REDR(bd1, bk1, sd1) REDR(bd2, bk2, sd2) REDR(bd3, bk3, sd3)
    REDR(bd4, bk4, sd4) REDR(bd5, bk5, sd5) REDR(bd6, bk6, sd6) REDR(bd7, bk7, sd7)
    if (m16 == 0) {
        const int base = 32 * w + 4 * q;
        idx_s[base + 0]      = (sd0 - bd0 <= TAU) ? -1 : bk0;
        idx_s[base + 1]      = (sd1 - bd1 <= TAU) ? -1 : bk1;
        idx_s[base + 2]      = (sd2 - bd2 <= TAU) ? -1 : bk2;
        idx_s[base + 3]      = (sd3 - bd3 <= TAU) ? -1 : bk3;
        idx_s[base + 16 + 0] = (sd4 - bd4 <= TAU) ? -1 : bk4;
        idx_s[base + 16 + 1] = (sd5 - bd5 <= TAU) ? -1 : bk5;
        idx_s[base + 16 + 2] = (sd6 - bd6 <= TAU) ? -1 : bk6;
        idx_s[base + 16 + 3] = (sd7 - bd7 <= TAU) ? -1 : bk7;
    }
    __syncthreads();

    // ---- compact flagged rows (skip scan when clean)
    if (t < 128 && idx_s[t] < 0) {
        const int s = atomicAdd(&nfb, 1);
        fbrows[s] = (unsigned char)t;
    }
    __syncthreads();
    const int nfbv = nfb;

    // ---- fallback: np-bit-exact rescan for flagged rows (rare).
    for (int fi = 0; fi < nfbv; ++fi) {
        const int row = fbrows[fi];
        if (t < 64) zrow_s[t] = zB[(size_t)t * HWz + s0 + row];
        __syncthreads();
        float zn;
        {   // np pairwise-8 znorm (broadcast LDS reads)
#pragma clang fp contract(off)
            float r0, r1, r2, r3, r4, r5, r6, r7;
            r0 = zrow_s[0]*zrow_s[0]; r1 = zrow_s[1]*zrow_s[1];
            r2 = zrow_s[2]*zrow_s[2]; r3 = zrow_s[3]*zrow_s[3];
            r4 = zrow_s[4]*zrow_s[4]; r5 = zrow_s[5]*zrow_s[5];
            r6 = zrow_s[6]*zrow_s[6]; r7 = zrow_s[7]*zrow_s[7];
#pragma unroll
            for (int m = 1; m < 8; ++m) {
                float v0 = zrow_s[8*m+0], v1 = zrow_s[8*m+1];
                float v2 = zrow_s[8*m+2], v3 = zrow_s[8*m+3];
                float v4 = zrow_s[8*m+4], v5 = zrow_s[8*m+5];
                float v6 = zrow_s[8*m+6], v7 = zrow_s[8*m+7];
                r0 = r0 + v0*v0; r1 = r1 + v1*v1; r2 = r2 + v2*v2; r3 = r3 + v3*v3;
                r4 = r4 + v4*v4; r5 = r5 + v5*v5; r6 = r6 + v6*v6; r7 = r7 + v7*v7;
            }
            zn = ((r0 + r1) + (r2 + r3)) + ((r4 + r5) + (r6 + r7));
        }
        float bd; int bk;
        {   // codes t and t+256, exact sequential-d chain (R5-validated)
            float dd[2];
#pragma unroll
            for (int h = 0; h < 2; ++h) {
                const int k = t + 256 * h;
                const float4* C = (const float4*)(cb + (size_t)k * 64);
                float a = 0.f;
#pragma unroll
                for (int i = 0; i < 16; ++i) {
                    const float4 c4 = C[i];
                    a = __builtin_fmaf(zrow_s[4*i+0], c4.x, a);
                    a = __builtin_fmaf(zrow_s[4*i+1], c4.y, a);
                    a = __builtin_fmaf(zrow_s[4*i+2], c4.z, a);
                    a = __builtin_fmaf(zrow_s[4*i+3], c4.w, a);
                }
                dd[h] = (zn - 2.0f * a) + cn_s[k];
            }
            bd = dd[0]; bk = t;
            if (dd[1] < bd) { bd = dd[1]; bk = t + 256; }
        }
#pragma unroll
        for (int mm = 1; mm < 64; mm <<= 1) {
            const float ob = __shfl_xor(bd, mm, 64);
            const int   ok = __shfl_xor(bk, mm, 64);
            if (ob < bd || (ob == bd && ok < bk)) { bd = ob; bk = ok; }
        }
        if (l == 0) { wredD[w] = bd; wredK[w] = bk; }
        __syncthreads();
        if (t == 0) {
            float fb = wredD[0]; int fk = wredK[0];
#pragma unroll
            for (int i = 1; i < 4; ++i) {
                if (wredD[i] < fb || (wredD[i] == fb && wredK[i] < fk)) {
                    fb = wredD[i]; fk = wredK[i];
                }
            }
            idx_s[row] = fk;
        }
        __syncthreads();
    }

    // ---- epilogue: gather code, write q_st (NCHW coalesced), loss.
    // y re-read from global (coalesced, L3-warm) -- bitwise same values as z.
    const int p  = t & 127;
    const int d0 = (t >> 7) * 32;
    const int myidx = idx_s[p];
    const float* qrow = cb + (size_t)myidx * 64 + d0;
    const float* zc = zB + s0 + p;
    float* oB = out + (size_t)b * (Dz * HWz) + s0 + p;
    float lsum = 0.f;
#pragma unroll
    for (int j = 0; j < 8; ++j) {
        const int d = d0 + 4 * j;
        const float4 q4 = *(const float4*)(qrow + 4 * j);
        const float y0 = zc[(size_t)(d + 0) * HWz];
        const float y1 = zc[(size_t)(d + 1) * HWz];
        const float y2 = zc[(size_t)(d + 2) * HWz];
        const float y3 = zc[(size_t)(d + 3) * HWz];
        const float e0 = y0 - q4.x, e1 = y1 - q4.y;
        const float e2 = y2 - q4.z, e3 = y3 - q4.w;
        lsum += e0 * e0; lsum += e1 * e1; lsum += e2 * e2; lsum += e3 * e3;
        oB[(size_t)(d + 0) * HWz] = y0 + (q4.x - y0);
        oB[(size_t)(d + 1) * HWz] = y1 + (q4.y - y1);
        oB[(size_t)(d + 2) * HWz] = y2 + (q4.z - y2);
        oB[(size_t)(d + 3) * HWz] = y3 + (q4.w - y3);
    }
#pragma unroll
    for (int off = 32; off > 0; off >>= 1) lsum += __shfl_down(lsum, off, 64);
    if (l == 0) wsum[w] = lsum;
    __syncthreads();
    if (t == 0) {
        float tot = (wsum[0] + wsum[1]) + (wsum[2] + wsum[3]);
        atomicAdd(loss_accum, tot);
        __threadfence();
        unsigned int ticket = atomicAdd(done_counter, 1u);
        if (ticket == gridDim.x - 1) {
            __threadfence();
            float total = atomicAdd(loss_accum, 0.0f);
            float X = total / (float)QSIZE;
            out[QSIZE] = X + 0.25f * X;
        }
    }
}

extern "C" void kernel_launch(void* const* d_in, const int* in_sizes, int n_in,
                              void* d_out, int out_size, void* d_ws, size_t ws_size,
                              hipStream_t stream) {
    const float* z  = (const float*)d_in[0];
    const float* cb = (const float*)d_in[1];
    float* out = (float*)d_out;
    unsigned short* cbws = (unsigned short*)d_ws;
    float* cnws = (float*)((char*)d_ws + CB_WS_BYTES);
    float* lossp = (float*)((char*)d_ws + CB_WS_BYTES + 2048);
    unsigned int* donep = (unsigned int*)(lossp + 1);
    hipMemsetAsync(lossp, 0, 8, stream);
    vq_prep<<<2, 256, 0, stream>>>(cb, cbws, cnws);
    vq_main<<<Nz / 128, 256, 0, stream>>>(z, cb, cbws, cnws, out, lossp, donep);
}

// Round 2
// 141.077 us; speedup vs baseline: 1.2109x; 1.1287x over previous
//
#include <hip/hip_runtime.h>

// VQ-VAE quantize: z [32,64,64,64] NCHW fp32, codebook [512,64] fp32.
// out = quantized (8388608 fp32, NCHW) ++ loss scalar. N=131072, D=64, K=512.
//
// R10: amortization + prep fix (R9 post-mortem: constant ~69us bench-vs-main
// gap -> vq_prep's 128 scalar 2B stores on 2 CUs suspected; vq_main still
// latency-idle with 2 residency rounds and per-block fixed costs over only
// 128 positions).
// - vq_prep: vectorized ushort8 (16B) split stores, 16 stores/thread instead
//   of 128; grid 8x64 so 8 CUs share the work.
// - vq_main: 256 positions/block (grid 512 -> ONE residency round at
//   2 blocks/CU). 4 position-tiles per wave share each B-fragment ->
//   2x MFMA:ds_read density; codebook staging traffic halves; per-position
//   fixed costs (A-build, epilogue, barriers) halve.
// Numerics unchanged: 3-pass hi/lo bf16 MFMA rank, TAU=4e-3 gap ->
// np-bit-exact block rescan; outputs are exact gathers -> absmax 0.0.

typedef __bf16 bf8 __attribute__((ext_vector_type(8)));
typedef float  f4  __attribute__((ext_vector_type(4)));
typedef unsigned short us8 __attribute__((ext_vector_type(8)));

#define Dz    64
#define HWz   4096
#define Nz    131072
#define QSIZE ((size_t)Nz * Dz)     // 8388608
#define CROW  72                    // split-cb row stride (ushorts) = 144B
#define TILE_USHORT 18432           // one 128-code tile (hi+lo) in ushorts
#define TILE_BYTES  36864
#define CB_WS_BYTES (4 * 36864)     // 147456
#define TAU   4e-3f
#define POSB  256                   // positions per block

#define MFMA(A, B, C) __builtin_amdgcn_mfma_f32_16x16x32_bf16(A, B, C, 0, 0, 0)

// wave-uniform LDS dest (base + lane*16), per-lane global src
__device__ __forceinline__ void gll16(const void* g, void* l) {
    __builtin_amdgcn_global_load_lds(
        (const __attribute__((address_space(1))) void*)g,
        (__attribute__((address_space(3))) void*)l, 16, 0, 0);
}

// ---------- prep: split codebook to bf16 hi/lo (padded tiles) + exact cn ----
__global__ __launch_bounds__(64) void vq_prep(const float* __restrict__ cb,
                                              unsigned short* __restrict__ cbws,
                                              float* __restrict__ cnws) {
    const int k = blockIdx.x * 64 + threadIdx.x;    // 0..511
    const float4* row = (const float4*)(cb + (size_t)k * 64);
    {   // numpy pairwise-8 sumsq (squares round before add)
#pragma clang fp contract(off)
        float r0, r1, r2, r3, r4, r5, r6, r7;
        {
            float4 f0 = row[0], f1 = row[1];
            r0 = f0.x * f0.x; r1 = f0.y * f0.y; r2 = f0.z * f0.z; r3 = f0.w * f0.w;
            r4 = f1.x * f1.x; r5 = f1.y * f1.y; r6 = f1.z * f1.z; r7 = f1.w * f1.w;
        }
#pragma unroll
        for (int m = 1; m < 8; ++m) {
            float4 f0 = row[2 * m], f1 = row[2 * m + 1];
            r0 = r0 + f0.x * f0.x; r1 = r1 + f0.y * f0.y;
            r2 = r2 + f0.z * f0.z; r3 = r3 + f0.w * f0.w;
            r4 = r4 + f1.x * f1.x; r5 = r5 + f1.y * f1.y;
            r6 = r6 + f1.z * f1.z; r7 = r7 + f1.w * f1.w;
        }
        cnws[k] = ((r0 + r1) + (r2 + r3)) + ((r4 + r5) + (r6 + r7));
    }
    // vectorized split: 8x us8 hi + 8x us8 lo, 16B stores (144B row stride
    // keeps 16B alignment: 144 % 16 == 0).
    unsigned short* hi = cbws + (size_t)(k >> 7) * TILE_USHORT + (k & 127) * CROW;
    unsigned short* lo = hi + TILE_USHORT / 2;      // +9216 ushorts = 18432B
    us8* hv = (us8*)hi;
    us8* lv = (us8*)lo;
#define SPLIT2(x, H, L, i)                                             \
    {   __bf16 h = (__bf16)(x); float rr = (x) - (float)h;             \
        H[i] = __builtin_bit_cast(unsigned short, h);                  \
        L[i] = __builtin_bit_cast(unsigned short, (__bf16)rr); }
#pragma unroll
    for (int c = 0; c < 8; ++c) {
        float4 f0 = row[2 * c], f1 = row[2 * c + 1];
        us8 h8, l8;
        SPLIT2(f0.x, h8, l8, 0) SPLIT2(f0.y, h8, l8, 1)
        SPLIT2(f0.z, h8, l8, 2) SPLIT2(f0.w, h8, l8, 3)
        SPLIT2(f1.x, h8, l8, 4) SPLIT2(f1.y, h8, l8, 5)
        SPLIT2(f1.z, h8, l8, 6) SPLIT2(f1.w, h8, l8, 7)
        hv[c] = h8;
        lv[c] = l8;
    }
#undef SPLIT2
}

// ---------- main ----------
// best/second update: order matters (second from OLD best).
#define UPDR(ACCE, B, K, S)                                            \
    {   const float vv = __builtin_fmaf(ACCE, -2.0f, cnv);             \
        S = fminf(S, fmaxf(B, vv));                                    \
        K = (vv < B) ? kcand : K;                                      \
        B = fminf(B, vv); }

#define REDR(B, K, S)                                                  \
    _Pragma("unroll")                                                  \
    for (int mm = 1; mm < 16; mm <<= 1) {                              \
        const float ob = __shfl_xor(B, mm, 64);                        \
        const int   ok = __shfl_xor(K, mm, 64);                        \
        const float os = __shfl_xor(S, mm, 64);                        \
        S = fminf(fminf(S, os), fmaxf(B, ob));                         \
        K = (ob < B) ? ok : K;                                         \
        B = fminf(B, ob); }

// per position-tile T: A-frags (hi/lo x 2 k-chunks) + best/second trackers
#define DECLT(T)                                                       \
    bf8 ah##T##0, ah##T##1, al##T##0, al##T##1;                        \
    float bd##T##0 = INF, bd##T##1 = INF, bd##T##2 = INF, bd##T##3 = INF; \
    float sd##T##0 = INF, sd##T##1 = INF, sd##T##2 = INF, sd##T##3 = INF; \
    int   bk##T##0 = 0, bk##T##1 = 0, bk##T##2 = 0, bk##T##3 = 0;

#define BUILDT(T, P)                                                   \
    _Pragma("unroll")                                                  \
    for (int j = 0; j < 8; ++j) {                                      \
        const float v0 = zq[(size_t)(q * 8 + j) * HWz + (P)];          \
        const float v1 = zq[(size_t)(32 + q * 8 + j) * HWz + (P)];     \
        const __bf16 h0 = (__bf16)v0, h1 = (__bf16)v1;                 \
        ah##T##0[j] = h0; al##T##0[j] = (__bf16)(v0 - (float)h0);      \
        ah##T##1[j] = h1; al##T##1[j] = (__bf16)(v1 - (float)h1);      \
    }

#define TILE_STEP(T)                                                   \
    {   f4 acc = {0.f, 0.f, 0.f, 0.f};                                 \
        acc = MFMA(ah##T##0, bh0, acc); acc = MFMA(ah##T##1, bh1, acc);\
        acc = MFMA(al##T##0, bh0, acc); acc = MFMA(al##T##1, bh1, acc);\
        acc = MFMA(ah##T##0, bl0, acc); acc = MFMA(ah##T##1, bl1, acc);\
        UPDR(acc[0], bd##T##0, bk##T##0, sd##T##0)                     \
        UPDR(acc[1], bd##T##1, bk##T##1, sd##T##1)                     \
        UPDR(acc[2], bd##T##2, bk##T##2, sd##T##2)                     \
        UPDR(acc[3], bd##T##3, bk##T##3, sd##T##3) }

#define REDT(T)                                                        \
    REDR(bd##T##0, bk##T##0, sd##T##0) REDR(bd##T##1, bk##T##1, sd##T##1) \
    REDR(bd##T##2, bk##T##2, sd##T##2) REDR(bd##T##3, bk##T##3, sd##T##3)

#define FLAGT(T, OFF)                                                  \
    idx_s[base + (OFF) + 0] = (sd##T##0 - bd##T##0 <= TAU) ? -1 : bk##T##0; \
    idx_s[base + (OFF) + 1] = (sd##T##1 - bd##T##1 <= TAU) ? -1 : bk##T##1; \
    idx_s[base + (OFF) + 2] = (sd##T##2 - bd##T##2 <= TAU) ? -1 : bk##T##2; \
    idx_s[base + (OFF) + 3] = (sd##T##3 - bd##T##3 <= TAU) ? -1 : bk##T##3;

__global__ __launch_bounds__(256, 2) void vq_main(
    const float* __restrict__ z, const float* __restrict__ cb,
    const unsigned short* __restrict__ cbws, const float* __restrict__ cnws,
    float* __restrict__ out, float* __restrict__ loss_accum,
    unsigned int* __restrict__ done_counter) {
    __shared__ __attribute__((aligned(16))) unsigned short cbS[2][TILE_USHORT];
    __shared__ __attribute__((aligned(16))) float cn_s[512];
    __shared__ int    idx_s[POSB];
    __shared__ float  zrow_s[64];
    __shared__ float  wredD[4];
    __shared__ int    wredK[4];
    __shared__ float  wsum[4];
    __shared__ int    nfb;
    __shared__ unsigned char fbrows[POSB];

    const int t  = threadIdx.x;
    const int w  = t >> 6;
    const int l  = t & 63;
    const int q  = l >> 4;
    const int m16 = l & 15;
    const int n0g = blockIdx.x * POSB;
    const int b   = n0g >> 12;
    const int s0  = n0g & 4095;
    const float* zB = z + (size_t)b * (Dz * HWz);

    // ---- issue tile0 + cn async into LDS
    {
        const char* tsrc = (const char*)cbws;
        char* tdst = (char*)&cbS[0][0];
#pragma unroll
        for (int i = 0; i < 9; ++i) {
            const int c = 9 * w + i;
            gll16(tsrc + c * 1024 + l * 16, tdst + c * 1024);
        }
        if (w < 2)
            gll16((const char*)cnws + w * 1024 + l * 16, (char*)cn_s + w * 1024);
        if (t == 0) nfb = 0;
    }

    // ---- build A fragments straight from global (overlaps tile0 staging)
    const float INF = __builtin_inff();
    DECLT(A) DECLT(B) DECLT(C) DECLT(D)
    {
        const int pA = 64 * w + m16;
        const float* zq = zB + s0;
        BUILDT(A, pA) BUILDT(B, pA + 16) BUILDT(C, pA + 32) BUILDT(D, pA + 48)
    }
    __syncthreads();    // vmcnt(0) drain: tile0 + cn landed

    // ---- K loop: 4 tiles x 128 codes, double-buffered w/ async prefetch.
    for (int kt = 0; kt < 4; ++kt) {
        const unsigned short* cbuf = &cbS[kt & 1][0];
        if (kt < 3) {   // issue next tile BEFORE compute; lands by next barrier
            const char* tsrc = (const char*)(cbws + (size_t)(kt + 1) * TILE_USHORT);
            char* tdst = (char*)&cbS[(kt + 1) & 1][0];
#pragma unroll
            for (int i = 0; i < 9; ++i) {
                const int c = 9 * w + i;
                gll16(tsrc + c * 1024 + l * 16, tdst + c * 1024);
            }
        }
        const int k0 = kt * 128;
        for (int n0 = 0; n0 < 128; n0 += 16) {
            const int nlane = n0 + m16;
            const int hoff = nlane * CROW + q * 8;          // ushorts
            const bf8 bh0 = *(const bf8*)(cbuf + hoff);
            const bf8 bh1 = *(const bf8*)(cbuf + hoff + 32);
            const bf8 bl0 = *(const bf8*)(cbuf + hoff + TILE_USHORT / 2);
            const bf8 bl1 = *(const bf8*)(cbuf + hoff + TILE_USHORT / 2 + 32);
            const float cnv = cn_s[k0 + nlane];
            const int kcand = k0 + nlane;
            TILE_STEP(A) TILE_STEP(B) TILE_STEP(C) TILE_STEP(D)
        }
        __syncthreads();    // all reads of cbuf done; next tile's gll drained
    }

    // ---- cross-lane reduce (16-lane groups hold one row each) + flag.
    REDT(A) REDT(B) REDT(C) REDT(D)
    if (m16 == 0) {
        const int base = 64 * w + 4 * q;
        FLAGT(A, 0) FLAGT(B, 16) FLAGT(C, 32) FLAGT(D, 48)
    }
    __syncthreads();

    // ---- compact flagged rows (skip scan when clean)
    if (idx_s[t] < 0) {
        const int s = atomicAdd(&nfb, 1);
        fbrows[s] = (unsigned char)t;
    }
    __syncthreads();
    const int nfbv = nfb;

    // ---- fallback: np-bit-exact rescan for flagged rows (rare).
    for (int fi = 0; fi < nfbv; ++fi) {
        const int row = fbrows[fi];
        if (t < 64) zrow_s[t] = zB[(size_t)t * HWz + s0 + row];
        __syncthreads();
        float zn;
        {   // np pairwise-8 znorm (broadcast LDS reads)
#pragma clang fp contract(off)
            float r0, r1, r2, r3, r4, r5, r6, r7;
            r0 = zrow_s[0]*zrow_s[0]; r1 = zrow_s[1]*zrow_s[1];
            r2 = zrow_s[2]*zrow_s[2]; r3 = zrow_s[3]*zrow_s[3];
            r4 = zrow_s[4]*zrow_s[4]; r5 = zrow_s[5]*zrow_s[5];
            r6 = zrow_s[6]*zrow_s[6]; r7 = zrow_s[7]*zrow_s[7];
#pragma unroll
            for (int m = 1; m < 8; ++m) {
                float v0 = zrow_s[8*m+0], v1 = zrow_s[8*m+1];
                float v2 = zrow_s[8*m+2], v3 = zrow_s[8*m+3];
                float v4 = zrow_s[8*m+4], v5 = zrow_s[8*m+5];
                float v6 = zrow_s[8*m+6], v7 = zrow_s[8*m+7];
                r0 = r0 + v0*v0; r1 = r1 + v1*v1; r2 = r2 + v2*v2; r3 = r3 + v3*v3;
                r4 = r4 + v4*v4; r5 = r5 + v5*v5; r6 = r6 + v6*v6; r7 = r7 + v7*v7;
            }
            zn = ((r0 + r1) + (r2 + r3)) + ((r4 + r5) + (r6 + r7));
        }
        float bd; int bk;
        {   // codes t and t+256, exact sequential-d chain (R5-validated)
            float dd[2];
#pragma unroll
            for (int h = 0; h < 2; ++h) {
                const int k = t + 256 * h;
                const float4* C = (const float4*)(cb + (size_t)k * 64);
                float a = 0.f;
#pragma unroll
                for (int i = 0; i < 16; ++i) {
                    const float4 c4 = C[i];
                    a = __builtin_fmaf(zrow_s[4*i+0], c4.x, a);
                    a = __builtin_fmaf(zrow_s[4*i+1], c4.y, a);
                    a = __builtin_fmaf(zrow_s[4*i+2], c4.z, a);
                    a = __builtin_fmaf(zrow_s[4*i+3], c4.w, a);
                }
                dd[h] = (zn - 2.0f * a) + cn_s[k];
            }
            bd = dd[0]; bk = t;
            if (dd[1] < bd) { bd = dd[1]; bk = t + 256; }
        }
#pragma unroll
        for (int mm = 1; mm < 64; mm <<= 1) {
            const float ob = __shfl_xor(bd, mm, 64);
            const int   ok = __shfl_xor(bk, mm, 64);
            if (ob < bd || (ob == bd && ok < bk)) { bd = ob; bk = ok; }
        }
        if (l == 0) { wredD[w] = bd; wredK[w] = bk; }
        __syncthreads();
        if (t == 0) {
            float fb = wredD[0]; int fk = wredK[0];
#pragma unroll
            for (int i = 1; i < 4; ++i) {
                if (wredD[i] < fb || (wredD[i] == fb && wredK[i] < fk)) {
                    fb = wredD[i]; fk = wredK[i];
                }
            }
            idx_s[row] = fk;
        }
        __syncthreads();
    }

    // ---- epilogue: gather code, write q_st (NCHW coalesced), loss.
    // One thread per position, full 64-d column. y re-read from global
    // (coalesced, L3-warm) -- bitwise same values as z.
    const int myidx = idx_s[t];
    const float* qrow = cb + (size_t)myidx * 64;
    const float* zc = zB + s0 + t;
    float* oB = out + (size_t)b * (Dz * HWz) + s0 + t;
    float lsum = 0.f;
#pragma unroll
    for (int j = 0; j < 16; ++j) {
        const int d = 4 * j;
        const float4 q4 = *(const float4*)(qrow + d);
        const float y0 = zc[(size_t)(d + 0) * HWz];
        const float y1 = zc[(size_t)(d + 1) * HWz];
        const float y2 = zc[(size_t)(d + 2) * HWz];
        const float y3 = zc[(size_t)(d + 3) * HWz];
        const float e0 = y0 - q4.x, e1 = y1 - q4.y;
        const float e2 = y2 - q4.z, e3 = y3 - q4.w;
        lsum += e0 * e0; lsum += e1 * e1; lsum += e2 * e2; lsum += e3 * e3;
        oB[(size_t)(d + 0) * HWz] = y0 + (q4.x - y0);
        oB[(size_t)(d + 1) * HWz] = y1 + (q4.y - y1);
        oB[(size_t)(d + 2) * HWz] = y2 + (q4.z - y2);
        oB[(size_t)(d + 3) * HWz] = y3 + (q4.w - y3);
    }
#pragma unroll
    for (int off = 32; off > 0; off >>= 1) lsum += __shfl_down(lsum, off, 64);
    if (l == 0) wsum[w] = lsum;
    __syncthreads();
    if (t == 0) {
        float tot = (wsum[0] + wsum[1]) + (wsum[2] + wsum[3]);
        atomicAdd(loss_accum, tot);
        __threadfence();
        unsigned int ticket = atomicAdd(done_counter, 1u);
        if (ticket == gridDim.x - 1) {
            __threadfence();
            float total = atomicAdd(loss_accum, 0.0f);
            float X = total / (float)QSIZE;
            out[QSIZE] = X + 0.25f * X;
        }
    }
}

extern "C" void kernel_launch(void* const* d_in, const int* in_sizes, int n_in,
                              void* d_out, int out_size, void* d_ws, size_t ws_size,
                              hipStream_t stream) {
    const float* z  = (const float*)d_in[0];
    const float* cb = (const float*)d_in[1];
    float* out = (float*)d_out;
    unsigned short* cbws = (unsigned short*)d_ws;
    float* cnws = (float*)((char*)d_ws + CB_WS_BYTES);
    float* lossp = (float*)((char*)d_ws + CB_WS_BYTES + 2048);
    unsigned int* donep = (unsigned int*)(lossp + 1);
    hipMemsetAsync(lossp, 0, 8, stream);
    vq_prep<<<8, 64, 0, stream>>>(cb, cbws, cnws);
    vq_main<<<Nz / POSB, 256, 0, stream>>>(z, cb, cbws, cnws, out, lossp, donep);
}